// Round 5
// baseline (178.892 us; speedup 1.0000x reference)
//
#include <hip/hip_runtime.h>

#define NCAP 5
#define DCAP 5
#define NO 25          // NCAP*DCAP
#define II 256
#define FF 80
#define NROUT 4
#define EPS 1e-7f
#define WSTR 104       // W LDS row stride in bf16
#define USTR 28        // u_lds row stride in f32 (112B, 16B-aligned rows)

typedef __attribute__((ext_vector_type(8))) short bf16x8;
typedef __attribute__((ext_vector_type(4))) float f32x4;

__device__ __forceinline__ int cvt2(float lo, float hi) {
    int r;
    asm("v_cvt_pk_bf16_f32 %0, %1, %2" : "=v"(r) : "v"(lo), "v"(hi));
    return r;
}

// split 8 consecutive f32 (two float4) into hi/lo bf16x8 fragments
__device__ __forceinline__ void cvt_hi_lo(const float4 a, const float4 c,
                                          bf16x8& hi, bf16x8& lo) {
    union { int i[4]; bf16x8 v; } H, L;
    H.i[0] = cvt2(a.x, a.y);
    H.i[1] = cvt2(a.z, a.w);
    H.i[2] = cvt2(c.x, c.y);
    H.i[3] = cvt2(c.z, c.w);
    const float h0 = __int_as_float(H.i[0] << 16);
    const float h1 = __int_as_float(H.i[0] & 0xFFFF0000);
    const float h2 = __int_as_float(H.i[1] << 16);
    const float h3 = __int_as_float(H.i[1] & 0xFFFF0000);
    const float h4 = __int_as_float(H.i[2] << 16);
    const float h5 = __int_as_float(H.i[2] & 0xFFFF0000);
    const float h6 = __int_as_float(H.i[3] << 16);
    const float h7 = __int_as_float(H.i[3] & 0xFFFF0000);
    L.i[0] = cvt2(a.x - h0, a.y - h1);
    L.i[1] = cvt2(a.z - h2, a.w - h3);
    L.i[2] = cvt2(c.x - h4, c.y - h5);
    L.i[3] = cvt2(c.z - h6, c.w - h7);
    hi = H.v; lo = L.v;
}

template<int CTRL>
__device__ __forceinline__ float dpp_add(float v) {
    int sw = __builtin_amdgcn_update_dpp(0, __float_as_int(v), CTRL, 0xF, 0xF, true);
    return v + __int_as_float(sw);
}
// sum within each 16-lane group, pure VALU
__device__ __forceinline__ float row16_sum(float v) {
    v = dpp_add<0xB1>(v);    // quad_perm(1,0,3,2)
    v = dpp_add<0x4E>(v);    // quad_perm(2,3,0,1)
    v = dpp_add<0x141>(v);   // row_half_mirror
    v = dpp_add<0x140>(v);   // row_mirror
    return v;
}

__global__ __launch_bounds__(256, 5)
void capsule_mfma(const float* __restrict__ x, const float* __restrict__ W,
                  float* __restrict__ out) {
    const int b    = blockIdx.x;
    const int t    = threadIdx.x;
    const int lane = t & 63;
    const int wv   = t >> 6;
    const int lr   = lane & 15;   // row/col within 16-tile
    const int lg   = lane >> 4;   // k-group / reg-group

    __shared__ __align__(16) float u_lds[II * USTR];          // 28672 B
    __shared__ __align__(16) float red[16 * 28];
    __shared__ __align__(16) float fsum[28];
    // W hi/lo staging aliases u_lds (dead before GEMM writes u_lds)
    unsigned short* Wh = reinterpret_cast<unsigned short*>(u_lds);
    unsigned short* Wl = Wh + 32 * WSTR;

    // ---- stage W -> hi/lo bf16 LDS (zero-pad o in [25,32), k in [80,104)) ----
    for (int idx = t; idx < 32 * WSTR; idx += 256) {
        const int o = idx / WSTR;
        const int k = idx - o * WSTR;
        const float v = (o < NO && k < FF) ? W[o * FF + k] : 0.f;
        const int hbits = cvt2(v, 0.f) & 0xFFFF;
        const float hf = __int_as_float(hbits << 16);
        Wh[idx] = (unsigned short)hbits;
        Wl[idx] = (unsigned short)(cvt2(v - hf, 0.f) & 0xFFFF);
    }
    __syncthreads();

    // ---- A-fragments (W) hi/lo: lane holds A[row=lr][k = ks*32 + lg*8 .. +7] ----
    bf16x8 Ah[2][3], Al[2][3];
#pragma unroll
    for (int ot = 0; ot < 2; ++ot)
#pragma unroll
        for (int ks = 0; ks < 3; ++ks) {
            Ah[ot][ks] = *reinterpret_cast<const bf16x8*>(
                &Wh[(ot * 16 + lr) * WSTR + ks * 32 + lg * 8]);
            Al[ot][ks] = *reinterpret_cast<const bf16x8*>(
                &Wl[(ot * 16 + lr) * WSTR + ks * 32 + lg * 8]);
        }
    __syncthreads();   // protect aliased u_lds

    // ---- GEMM: wave wv owns x-rows [wv*64, wv*64+64) ----
    const int R0 = wv * 64;
    const float* __restrict__ xbase = x + (size_t)b * II * FF;

#pragma unroll
    for (int nt = 0; nt < 4; ++nt) {
        const int xrow = R0 + nt * 16 + lr;
        const float* __restrict__ xp = xbase + (size_t)xrow * FF + lg * 8;

        bf16x8 Bh[3], Bl[3];
#pragma unroll
        for (int ks = 0; ks < 3; ++ks) {
            const int k = ks * 32 + lg * 8;
            if (k < FF) {
                const float4 a = *reinterpret_cast<const float4*>(xp + ks * 32);
                const float4 c = *reinterpret_cast<const float4*>(xp + ks * 32 + 4);
                cvt_hi_lo(a, c, Bh[ks], Bl[ks]);
            } else {
                const bf16x8 z = {0, 0, 0, 0, 0, 0, 0, 0};
                Bh[ks] = z; Bl[ks] = z;
            }
        }

        f32x4 acc0 = {0.f, 0.f, 0.f, 0.f};
        f32x4 acc1 = {0.f, 0.f, 0.f, 0.f};
        // interleave the two accumulator chains for 2-way MFMA ILP
#pragma unroll
        for (int ks = 0; ks < 3; ++ks) {
            acc0 = __builtin_amdgcn_mfma_f32_16x16x32_bf16(Ah[0][ks], Bl[ks], acc0, 0, 0, 0);
            acc1 = __builtin_amdgcn_mfma_f32_16x16x32_bf16(Ah[1][ks], Bl[ks], acc1, 0, 0, 0);
            acc0 = __builtin_amdgcn_mfma_f32_16x16x32_bf16(Al[0][ks], Bh[ks], acc0, 0, 0, 0);
            acc1 = __builtin_amdgcn_mfma_f32_16x16x32_bf16(Al[1][ks], Bh[ks], acc1, 0, 0, 0);
            acc0 = __builtin_amdgcn_mfma_f32_16x16x32_bf16(Ah[0][ks], Bh[ks], acc0, 0, 0, 0);
            acc1 = __builtin_amdgcn_mfma_f32_16x16x32_bf16(Ah[1][ks], Bh[ks], acc1, 0, 0, 0);
        }

        // C: lane holds col (xrow)=lr, rows o = ot*16 + lg*4 + reg
        *reinterpret_cast<float4*>(&u_lds[xrow * USTR + lg * 4]) =
            *reinterpret_cast<float4*>(&acc0);
        if (lg < 3)  // skip o in [28,32)
            *reinterpret_cast<float4*>(&u_lds[xrow * USTR + 16 + lg * 4]) =
                *reinterpret_cast<float4*>(&acc1);
    }
    // NOTE: no __syncthreads needed — each wave reads back only rows it wrote;
    // same-wave DS ops complete in order (compiler inserts lgkmcnt).

    // ---- read back this thread's row of u ----
    float u[NO];
#pragma unroll
    for (int q = 0; q < 6; ++q) {
        const float4 v4 = *reinterpret_cast<const float4*>(&u_lds[t * USTR + q * 4]);
        u[q * 4] = v4.x; u[q * 4 + 1] = v4.y; u[q * 4 + 2] = v4.z; u[q * 4 + 3] = v4.w;
    }
    u[24] = u_lds[t * USTR + 24];

    // ---- dynamic routing ----
    float bb[NCAP];
#pragma unroll
    for (int n = 0; n < NCAP; ++n) bb[n] = 0.f;

#pragma unroll
    for (int r = 0; r < NROUT; ++r) {
        float c[NCAP];
        if (r == 0) {
#pragma unroll
            for (int n = 0; n < NCAP; ++n) c[n] = 0.2f;
        } else {
            float m = bb[0];
#pragma unroll
            for (int n = 1; n < NCAP; ++n) m = fmaxf(m, bb[n]);
            float ssum = 0.f;
#pragma unroll
            for (int n = 0; n < NCAP; ++n) { c[n] = __expf(bb[n] - m); ssum += c[n]; }
            const float inv = __frcp_rn(ssum);
#pragma unroll
            for (int n = 0; n < NCAP; ++n) c[n] *= inv;
        }

        float p[NO];
#pragma unroll
        for (int o = 0; o < NO; ++o) p[o] = row16_sum(c[o / DCAP] * u[o]);

        if ((t & 15) == 0) {
            float* rg = &red[(t >> 4) * 28];
#pragma unroll
            for (int q = 0; q < 6; ++q)
                *reinterpret_cast<float4*>(&rg[q * 4]) =
                    make_float4(p[q * 4], p[q * 4 + 1], p[q * 4 + 2], p[q * 4 + 3]);
            rg[24] = p[24];
        }
        __syncthreads();

        if (t < NO) {
            float ssum = 0.f;
#pragma unroll
            for (int g = 0; g < 16; ++g) ssum += red[g * 28 + t];
            fsum[t] = ssum;
        }
        __syncthreads();

        if (r < NROUT - 1) {
            float s[NO];
#pragma unroll
            for (int q = 0; q < 6; ++q) {
                const float4 sv = *reinterpret_cast<const float4*>(&fsum[q * 4]);
                s[q * 4 + 0] = sv.x; s[q * 4 + 1] = sv.y;
                s[q * 4 + 2] = sv.z; s[q * 4 + 3] = sv.w;
            }
            s[24] = fsum[24];
#pragma unroll
            for (int n = 0; n < NCAP; ++n) {
                float sn = 0.f, dot = 0.f;
#pragma unroll
                for (int d = 0; d < DCAP; ++d) {
                    const float sv = s[n * DCAP + d];
                    sn  = fmaf(sv, sv, sn);
                    dot = fmaf(sv, u[n * DCAP + d], dot);
                }
                const float scale = sn * __frsqrt_rn(sn + EPS) * __frcp_rn(1.f + sn);
                bb[n] += dot * scale;
            }
        } else {
            if (t < NO) {
                const int n0 = (t / DCAP) * DCAP;
                float sn = 0.f;
#pragma unroll
                for (int d = 0; d < DCAP; ++d) {
                    const float sv = fsum[n0 + d];
                    sn = fmaf(sv, sv, sn);
                }
                const float scale = sn * __frsqrt_rn(sn + EPS) * __frcp_rn(1.f + sn);
                out[(size_t)b * NO + t] = fsum[t] * scale;
            }
        }
    }
}

extern "C" void kernel_launch(void* const* d_in, const int* in_sizes, int n_in,
                              void* d_out, int out_size, void* d_ws, size_t ws_size,
                              hipStream_t stream) {
    const float* x = (const float*)d_in[0];   // [8192, 256, 80]
    const float* W = (const float*)d_in[1];   // [25, 80]
    float* out = (float*)d_out;               // [8192, 5, 5]
    (void)in_sizes; (void)n_in; (void)out_size; (void)d_ws; (void)ws_size;

    capsule_mfma<<<dim3(8192), dim3(256), 0, stream>>>(x, W, out);
}

// Round 7
// 125.307 us; speedup vs baseline: 1.4276x; 1.4276x over previous
//
#include <hip/hip_runtime.h>

#define NCAP 5
#define DCAP 5
#define NO 25          // NCAP*DCAP
#define II 256
#define FF 80
#define NROUT 4
#define EPS 1e-7f
#define USTR 28        // u_lds row stride in f32 (112B, 16B-aligned rows)

typedef _Float16 f16x8 __attribute__((ext_vector_type(8)));
typedef __fp16 fp16x2 __attribute__((ext_vector_type(2)));
typedef float f32x4 __attribute__((ext_vector_type(4)));

// pack 8 consecutive f32 (two float4) into one f16x8 fragment (4 VALU ops)
__device__ __forceinline__ f16x8 pack8(const float4 a, const float4 c) {
    union { fp16x2 p[4]; f16x8 v; } u;
    u.p[0] = __builtin_amdgcn_cvt_pkrtz(a.x, a.y);
    u.p[1] = __builtin_amdgcn_cvt_pkrtz(a.z, a.w);
    u.p[2] = __builtin_amdgcn_cvt_pkrtz(c.x, c.y);
    u.p[3] = __builtin_amdgcn_cvt_pkrtz(c.z, c.w);
    return u.v;
}

template<int CTRL>
__device__ __forceinline__ float dpp_add(float v) {
    int sw = __builtin_amdgcn_update_dpp(0, __float_as_int(v), CTRL, 0xF, 0xF, true);
    return v + __int_as_float(sw);
}
// sum within each 16-lane group, pure VALU
__device__ __forceinline__ float row16_sum(float v) {
    v = dpp_add<0xB1>(v);    // quad_perm(1,0,3,2)
    v = dpp_add<0x4E>(v);    // quad_perm(2,3,0,1)
    v = dpp_add<0x141>(v);   // row_half_mirror
    v = dpp_add<0x140>(v);   // row_mirror
    return v;
}

__global__ __launch_bounds__(256, 5)
void capsule_mfma(const float* __restrict__ x, const float* __restrict__ W,
                  float* __restrict__ out) {
    const int b    = blockIdx.x;
    const int t    = threadIdx.x;
    const int lane = t & 63;
    const int wv   = t >> 6;
    const int lr   = lane & 15;   // row/col within 16-tile
    const int lg   = lane >> 4;   // k-group / reg-group

    __shared__ __align__(16) float u_lds[II * USTR];   // 28672 B
    __shared__ __align__(16) float red[16 * 28];
    __shared__ __align__(16) float fsum[28];

    // ---- A-fragments (W) straight from global (8 KB, L2-hot). No LDS, no barrier.
    // lane holds A[row = ot*16+lr][k = ks*32 + lg*8 .. +7]
    f16x8 Af[2][3];
#pragma unroll
    for (int ot = 0; ot < 2; ++ot)
#pragma unroll
        for (int ks = 0; ks < 3; ++ks) {
            const int row = ot * 16 + lr;
            const int k0  = ks * 32 + lg * 8;
            if (row < NO && k0 < FF) {
                const float4 a = *reinterpret_cast<const float4*>(&W[row * FF + k0]);
                const float4 c = *reinterpret_cast<const float4*>(&W[row * FF + k0 + 4]);
                Af[ot][ks] = pack8(a, c);
            } else {
                const f16x8 z = {};
                Af[ot][ks] = z;
            }
        }

    // ---- GEMM: wave wv owns x-rows [wv*64, wv*64+64) ----
    const int R0 = wv * 64;
    const float* __restrict__ xbase = x + (size_t)b * II * FF;

#pragma unroll
    for (int nt = 0; nt < 4; ++nt) {
        const int xrow = R0 + nt * 16 + lr;
        const float* __restrict__ xp = xbase + (size_t)xrow * FF;

        f16x8 Bf[3];
#pragma unroll
        for (int ks = 0; ks < 3; ++ks) {
            const int k0 = ks * 32 + lg * 8;
            if (k0 < FF) {
                const float4 a = *reinterpret_cast<const float4*>(xp + k0);
                const float4 c = *reinterpret_cast<const float4*>(xp + k0 + 4);
                Bf[ks] = pack8(a, c);
            } else {
                const f16x8 z = {};
                Bf[ks] = z;
            }
        }

        f32x4 acc0 = {0.f, 0.f, 0.f, 0.f};
        f32x4 acc1 = {0.f, 0.f, 0.f, 0.f};
#pragma unroll
        for (int ks = 0; ks < 3; ++ks) {
            acc0 = __builtin_amdgcn_mfma_f32_16x16x32_f16(Af[0][ks], Bf[ks], acc0, 0, 0, 0);
            acc1 = __builtin_amdgcn_mfma_f32_16x16x32_f16(Af[1][ks], Bf[ks], acc1, 0, 0, 0);
        }

        // C: lane holds col (xrow)=lr, rows o = ot*16 + lg*4 + reg
        *reinterpret_cast<float4*>(&u_lds[xrow * USTR + lg * 4]) =
            *reinterpret_cast<float4*>(&acc0);
        if (lg < 3)  // skip o in [28,32)
            *reinterpret_cast<float4*>(&u_lds[xrow * USTR + 16 + lg * 4]) =
                *reinterpret_cast<float4*>(&acc1);
    }
    // each wave reads back only rows it wrote; same-wave DS ordering suffices

    // ---- read back this thread's row of u ----
    float u[NO];
#pragma unroll
    for (int q = 0; q < 6; ++q) {
        const float4 v4 = *reinterpret_cast<const float4*>(&u_lds[t * USTR + q * 4]);
        u[q * 4] = v4.x; u[q * 4 + 1] = v4.y; u[q * 4 + 2] = v4.z; u[q * 4 + 3] = v4.w;
    }
    u[24] = u_lds[t * USTR + 24];

    // ---- dynamic routing ----
    float bb[NCAP];
#pragma unroll
    for (int n = 0; n < NCAP; ++n) bb[n] = 0.f;

#pragma unroll
    for (int r = 0; r < NROUT; ++r) {
        float c[NCAP];
        if (r == 0) {
#pragma unroll
            for (int n = 0; n < NCAP; ++n) c[n] = 0.2f;
        } else {
            float m = bb[0];
#pragma unroll
            for (int n = 1; n < NCAP; ++n) m = fmaxf(m, bb[n]);
            float ssum = 0.f;
#pragma unroll
            for (int n = 0; n < NCAP; ++n) { c[n] = __expf(bb[n] - m); ssum += c[n]; }
            const float inv = __frcp_rn(ssum);
#pragma unroll
            for (int n = 0; n < NCAP; ++n) c[n] *= inv;
        }

        float p[NO];
#pragma unroll
        for (int o = 0; o < NO; ++o) p[o] = row16_sum(c[o / DCAP] * u[o]);

        if ((t & 15) == 0) {
            float* rg = &red[(t >> 4) * 28];
#pragma unroll
            for (int q = 0; q < 6; ++q)
                *reinterpret_cast<float4*>(&rg[q * 4]) =
                    make_float4(p[q * 4], p[q * 4 + 1], p[q * 4 + 2], p[q * 4 + 3]);
            rg[24] = p[24];
        }
        __syncthreads();

        if (t < NO) {
            float ssum = 0.f;
#pragma unroll
            for (int g = 0; g < 16; ++g) ssum += red[g * 28 + t];
            fsum[t] = ssum;
        }
        __syncthreads();

        if (r < NROUT - 1) {
            float s[NO];
#pragma unroll
            for (int q = 0; q < 6; ++q) {
                const float4 sv = *reinterpret_cast<const float4*>(&fsum[q * 4]);
                s[q * 4 + 0] = sv.x; s[q * 4 + 1] = sv.y;
                s[q * 4 + 2] = sv.z; s[q * 4 + 3] = sv.w;
            }
            s[24] = fsum[24];
#pragma unroll
            for (int n = 0; n < NCAP; ++n) {
                float sn = 0.f, dot = 0.f;
#pragma unroll
                for (int d = 0; d < DCAP; ++d) {
                    const float sv = s[n * DCAP + d];
                    sn  = fmaf(sv, sv, sn);
                    dot = fmaf(sv, u[n * DCAP + d], dot);
                }
                const float scale = sn * __frsqrt_rn(sn + EPS) * __frcp_rn(1.f + sn);
                bb[n] += dot * scale;
            }
        } else {
            if (t < NO) {
                const int n0 = (t / DCAP) * DCAP;
                float sn = 0.f;
#pragma unroll
                for (int d = 0; d < DCAP; ++d) {
                    const float sv = fsum[n0 + d];
                    sn = fmaf(sv, sv, sn);
                }
                const float scale = sn * __frsqrt_rn(sn + EPS) * __frcp_rn(1.f + sn);
                out[(size_t)b * NO + t] = fsum[t] * scale;
            }
        }
    }
}

extern "C" void kernel_launch(void* const* d_in, const int* in_sizes, int n_in,
                              void* d_out, int out_size, void* d_ws, size_t ws_size,
                              hipStream_t stream) {
    const float* x = (const float*)d_in[0];   // [8192, 256, 80]
    const float* W = (const float*)d_in[1];   // [25, 80]
    float* out = (float*)d_out;               // [8192, 5, 5]
    (void)in_sizes; (void)n_in; (void)out_size; (void)d_ws; (void)ws_size;

    capsule_mfma<<<dim3(8192), dim3(256), 0, stream>>>(x, W, out);
}